// Round 1
// baseline (136.170 us; speedup 1.0000x reference)
//
#include <hip/hip_runtime.h>
#include <hip/hip_bf16.h>
#include <math.h>

// Problem constants
#define BB 64
#define QQ 100
#define NN 16
#define CC 2048            // NUM_CLASSES + 1
#define TIME_WEIGHT 2.0f
#define EOS_COEF 0.1f

// ---------------------------------------------------------------------------
// Kernel 1: logZ[b,q] = logsumexp(pred_logits[b,q,:]) over 2048 classes.
// One block per (b,q); 256 threads; each thread reads 8 floats (2x float4).
// ---------------------------------------------------------------------------
__global__ __launch_bounds__(256) void lse_kernel(const float* __restrict__ logits,
                                                  float* __restrict__ logZ) {
    const int bq = blockIdx.x;                 // 0 .. B*Q-1
    const float4* row = (const float4*)(logits + (size_t)bq * CC);
    const int t = threadIdx.x;
    float4 a = row[t];
    float4 b = row[t + 256];
    float m = fmaxf(fmaxf(fmaxf(a.x, a.y), fmaxf(a.z, a.w)),
                    fmaxf(fmaxf(b.x, b.y), fmaxf(b.z, b.w)));
    __shared__ float red[256];
    red[t] = m;
    __syncthreads();
    for (int s = 128; s > 0; s >>= 1) {
        if (t < s) red[t] = fmaxf(red[t], red[t + s]);
        __syncthreads();
    }
    m = red[0];
    __syncthreads();
    float sum = expf(a.x - m) + expf(a.y - m) + expf(a.z - m) + expf(a.w - m) +
                expf(b.x - m) + expf(b.y - m) + expf(b.z - m) + expf(b.w - m);
    red[t] = sum;
    __syncthreads();
    for (int s = 128; s > 0; s >>= 1) {
        if (t < s) red[t] += red[t + s];
        __syncthreads();
    }
    if (t == 0) logZ[bq] = m + logf(red[0]);
}

// ---------------------------------------------------------------------------
// Kernel 2: cost matrix, stored TRANSPOSED per batch: Cg[b][n][q] (16x100).
//   C = -softmax(logits)[label] + 2*|pred_time - timestamp|, nan_to_num'd.
// ---------------------------------------------------------------------------
__global__ __launch_bounds__(256) void cost_kernel(const float* __restrict__ logits,
                                                   const float* __restrict__ ptime,
                                                   const int* __restrict__ labels,
                                                   const float* __restrict__ tstamp,
                                                   const float* __restrict__ logZ,
                                                   float* __restrict__ Cg) {
    int idx = blockIdx.x * blockDim.x + threadIdx.x;   // b*1600 + n*100 + q
    if (idx >= BB * NN * QQ) return;
    int b = idx / (NN * QQ);
    int rem = idx % (NN * QQ);
    int n = rem / QQ;
    int q = rem % QQ;
    int lab = labels[b * NN + n];
    int bq = b * QQ + q;
    float lz = logZ[bq];
    float lg = logits[(size_t)bq * CC + lab];
    float cc = -expf(lg - lz);                           // -softmax prob at label
    float ct = fabsf(ptime[bq] - tstamp[b * NN + n]);
    float v = cc + TIME_WEIGHT * ct;
    if (isnan(v)) v = 100.0f;
    else if (isinf(v)) v = (v > 0.f) ? 100.0f : -100.0f;
    Cg[idx] = v;
}

// ---------------------------------------------------------------------------
// Kernel 3: Jonker-Volgenant assignment, one wave (64 threads) per batch.
// cost[r][c] = Cg[b][r][c]  (r = target row 0..15, c = query col 0..99).
// Exactly mirrors the reference _lsa: double arithmetic, same op order,
// argmin tie-break = lowest column index.
// Output: qs[b*16 + r] = matched query column for target r.
// ---------------------------------------------------------------------------
__global__ __launch_bounds__(64) void hungarian_kernel(const float* __restrict__ Cg,
                                                       int* __restrict__ qs) {
    const int b = blockIdx.x;
    const int t = threadIdx.x;

    __shared__ double cost[NN][QQ];     // 12.8 KB
    __shared__ double u[NN + 1];
    __shared__ int p[QQ + 1];
    __shared__ int way[QQ + 1];

    for (int idx = t; idx < NN * QQ; idx += 64) {
        cost[idx / QQ][idx % QQ] = (double)Cg[(size_t)b * NN * QQ + idx];
    }
    for (int idx = t; idx <= QQ; idx += 64) p[idx] = 0;
    if (t <= NN) u[t] = 0.0;

    // Each lane owns columns jc0 = t+1 and (if <=100) jc1 = t+65 (1-based).
    const int jc0 = t + 1;
    const int jc1 = t + 65;
    const bool has2 = (jc1 <= QQ);
    double v0 = 0.0, v1 = 0.0;          // potentials for owned columns
    const double INF = __builtin_inf();

    __syncthreads();

    for (int i = 1; i <= NN; ++i) {
        double minv0 = INF, minv1 = INF;
        bool used0 = false, used1 = false;
        if (t == 0) p[0] = i;
        int j0 = 0;
        __syncthreads();                 // p[0] visible

        while (true) {
            // mark j0 used (column 0 is implicitly always used; handled below)
            if (j0 == jc0) used0 = true;
            if (j0 == jc1) used1 = true;
            int i0 = p[j0];
            double ui0 = u[i0];

            double bestv = INF;
            int bestj = 0x7FFFFFFF;
            if (!used0) {
                double cur = cost[i0 - 1][jc0 - 1] - ui0 - v0;
                if (cur < minv0) { minv0 = cur; way[jc0] = j0; }
                bestv = minv0; bestj = jc0;
            }
            if (has2 && !used1) {
                double cur = cost[i0 - 1][jc1 - 1] - ui0 - v1;
                if (cur < minv1) { minv1 = cur; way[jc1] = j0; }
                if (minv1 < bestv) { bestv = minv1; bestj = jc1; }  // tie keeps jc0 (lower)
            }
            // wave-wide argmin, tie-break lowest column index
            for (int s = 32; s > 0; s >>= 1) {
                double ov = __shfl_down(bestv, s, 64);
                int oj = __shfl_down(bestj, s, 64);
                if (ov < bestv || (ov == bestv && oj < bestj)) { bestv = ov; bestj = oj; }
            }
            double delta = __shfl(bestv, 0, 64);
            int j1 = __shfl(bestj, 0, 64);

            __syncthreads();             // all u reads done before u writes

            if (t == 0) u[p[0]] += delta;                 // column 0 (always used)
            if (used0) { u[p[jc0]] += delta; v0 -= delta; } else { minv0 -= delta; }
            if (has2) {
                if (used1) { u[p[jc1]] += delta; v1 -= delta; } else { minv1 -= delta; }
            }
            j0 = j1;
            __syncthreads();             // u/way writes visible
            if (p[j0] == 0) break;       // uniform
        }

        if (t == 0) {                    // augment along alternating path
            int jj = j0;
            while (jj != 0) {
                int jn = way[jj];
                p[jj] = p[jn];
                jj = jn;
            }
        }
        __syncthreads();
    }

    for (int idx = t + 1; idx <= QQ; idx += 64) {
        int r = p[idx];
        if (r > 0) qs[b * NN + (r - 1)] = idx - 1;
    }
}

// ---------------------------------------------------------------------------
// Kernel 4: scatter matched classes into match_class[b*Q + qcol] and
// accumulate the L1 timestamp loss numerator.
// ---------------------------------------------------------------------------
__global__ __launch_bounds__(256) void scatter_kernel(const int* __restrict__ qs,
                                                      const int* __restrict__ labels,
                                                      const float* __restrict__ ptime,
                                                      const float* __restrict__ tstamp,
                                                      int* __restrict__ match_class,
                                                      float* __restrict__ sums) {
    int idx = blockIdx.x * blockDim.x + threadIdx.x;   // b*16 + n
    float d = 0.f;
    if (idx < BB * NN) {
        int b = idx / NN;
        int qcol = qs[idx];
        match_class[b * QQ + qcol] = labels[idx];
        d = fabsf(ptime[b * QQ + qcol] - tstamp[idx]);
    }
    __shared__ float red[256];
    int t = threadIdx.x;
    red[t] = d;
    __syncthreads();
    for (int s = 128; s > 0; s >>= 1) {
        if (t < s) red[t] += red[t + s];
        __syncthreads();
    }
    if (t == 0) atomicAdd(&sums[2], red[0]);
}

// ---------------------------------------------------------------------------
// Kernel 5: weighted CE over all (b,q): nll = logZ - logit[target_class],
// w = 1 (matched) or EOS_COEF (class 0). Accumulate sum(w*nll), sum(w).
// ---------------------------------------------------------------------------
__global__ __launch_bounds__(256) void ce_kernel(const float* __restrict__ logits,
                                                 const float* __restrict__ logZ,
                                                 const int* __restrict__ match_class,
                                                 float* __restrict__ sums) {
    int idx = blockIdx.x * blockDim.x + threadIdx.x;   // b*Q + q
    float wn = 0.f, w = 0.f;
    if (idx < BB * QQ) {
        int tc = match_class[idx];
        float nll = logZ[idx] - logits[(size_t)idx * CC + tc];
        w = (tc == 0) ? EOS_COEF : 1.0f;
        wn = w * nll;
    }
    __shared__ float r1[256], r2[256];
    int t = threadIdx.x;
    r1[t] = wn; r2[t] = w;
    __syncthreads();
    for (int s = 128; s > 0; s >>= 1) {
        if (t < s) { r1[t] += r1[t + s]; r2[t] += r2[t + s]; }
        __syncthreads();
    }
    if (t == 0) { atomicAdd(&sums[0], r1[0]); atomicAdd(&sums[1], r2[0]); }
}

// ---------------------------------------------------------------------------
// Kernel 6: finalize scalar loss.
// ---------------------------------------------------------------------------
__global__ void fin_kernel(const float* __restrict__ sums, float* __restrict__ out) {
    out[0] = sums[0] / sums[1] + TIME_WEIGHT * (sums[2] / (float)(BB * NN));
}

// ---------------------------------------------------------------------------
// Workspace layout (bytes):
//   [0,16)          : float sums[4]  {sum_w_nll, sum_w, sum_time, pad}   (zeroed)
//   [16, 25616)     : int   match_class[6400]                            (zeroed)
//   [25616, 51216)  : float logZ[6400]
//   [51216, 460816) : float Cg[64*16*100]
//   [460816, 464912): int   qs[64*16]
// ---------------------------------------------------------------------------
extern "C" void kernel_launch(void* const* d_in, const int* in_sizes, int n_in,
                              void* d_out, int out_size, void* d_ws, size_t ws_size,
                              hipStream_t stream) {
    const float* logits = (const float*)d_in[0];   // [B,Q,2048]
    const float* ptime  = (const float*)d_in[1];   // [B,Q,1]
    const int*   labels = (const int*)d_in[2];     // [B,N]
    const float* tstamp = (const float*)d_in[3];   // [B,N,1]
    float* out = (float*)d_out;

    char* ws = (char*)d_ws;
    float* sums        = (float*)ws;
    int*   match_class = (int*)(ws + 16);
    float* logZ        = (float*)(ws + 25616);
    float* Cg          = (float*)(ws + 51216);
    int*   qs          = (int*)(ws + 460816);

    hipMemsetAsync(ws, 0, 25616, stream);   // zero sums + match_class

    lse_kernel<<<BB * QQ, 256, 0, stream>>>(logits, logZ);
    cost_kernel<<<(BB * NN * QQ + 255) / 256, 256, 0, stream>>>(
        logits, ptime, labels, tstamp, logZ, Cg);
    hungarian_kernel<<<BB, 64, 0, stream>>>(Cg, qs);
    scatter_kernel<<<(BB * NN + 255) / 256, 256, 0, stream>>>(
        qs, labels, ptime, tstamp, match_class, sums);
    ce_kernel<<<(BB * QQ + 255) / 256, 256, 0, stream>>>(
        logits, logZ, match_class, sums);
    fin_kernel<<<1, 1, 0, stream>>>(sums, out);
}

// Round 2
// 124.944 us; speedup vs baseline: 1.0898x; 1.0898x over previous
//
#include <hip/hip_runtime.h>
#include <hip/hip_bf16.h>
#include <math.h>

// Problem constants
#define BB 64
#define QQ 100
#define NN 16
#define CC 2048            // NUM_CLASSES + 1
#define TIME_WEIGHT 2.0f
#define EOS_COEF 0.1f

// ---------------------------------------------------------------------------
// Kernel 1: per (b,q) row (one wave each):
//   logZ[b,q] = logsumexp(logits[b,q,:])
//   Cg[b][n][q] = -softmax[label_n] + 2*|pt - ts_n|   (transposed cost matrix)
//   lsepart[block] = sum over 4 rows of (logZ - logit[class 0])   [EOS nll]
// 1600 blocks x 256 threads (4 waves = 4 rows per block).
// ---------------------------------------------------------------------------
__global__ __launch_bounds__(256) void lse_cost_kernel(
    const float* __restrict__ logits, const float* __restrict__ ptime,
    const int* __restrict__ labels, const float* __restrict__ tstamp,
    float* __restrict__ logZ, float* __restrict__ Cg,
    float* __restrict__ lsepart)
{
    const int wave = threadIdx.x >> 6;
    const int lane = threadIdx.x & 63;
    const int bq = blockIdx.x * 4 + wave;          // < 6400
    const int b = bq / QQ, q = bq % QQ;
    const float4* row4 = (const float4*)(logits + (size_t)bq * CC);

    float4 v[8];
    #pragma unroll
    for (int c = 0; c < 8; ++c) v[c] = row4[c * 64 + lane];

    float m = -INFINITY;
    #pragma unroll
    for (int c = 0; c < 8; ++c)
        m = fmaxf(m, fmaxf(fmaxf(v[c].x, v[c].y), fmaxf(v[c].z, v[c].w)));
    #pragma unroll
    for (int s = 1; s < 64; s <<= 1) m = fmaxf(m, __shfl_xor(m, s, 64));

    float sum = 0.f;
    #pragma unroll
    for (int c = 0; c < 8; ++c)
        sum += expf(v[c].x - m) + expf(v[c].y - m) +
               expf(v[c].z - m) + expf(v[c].w - m);
    #pragma unroll
    for (int s = 1; s < 64; s <<= 1) sum += __shfl_xor(sum, s, 64);

    const float lz = m + logf(sum);
    if (lane == 0) logZ[bq] = lz;

    // cost-matrix entries (lanes 0..15: one target each)
    const float pt = ptime[bq];
    if (lane < NN) {
        int lab = labels[b * NN + lane];
        float lg = logits[(size_t)bq * CC + lab];     // L1/L2-hot gather
        float cc = -expf(lg - lz);
        float ct = fabsf(pt - tstamp[b * NN + lane]);
        float val = cc + TIME_WEIGHT * ct;
        if (isnan(val)) val = 100.0f;
        else if (isinf(val)) val = (val > 0.f) ? 100.0f : -100.0f;
        Cg[((size_t)b * NN + lane) * QQ + q] = val;
    }

    // EOS nll partial: nll0 = logZ - logit[class 0]
    __shared__ float red[4];
    if (lane == 0) red[wave] = lz - logits[(size_t)bq * CC];
    __syncthreads();
    if (threadIdx.x == 0)
        lsepart[blockIdx.x] = red[0] + red[1] + red[2] + red[3];
}

// ---------------------------------------------------------------------------
// Kernel 2: Jonker-Volgenant assignment, one wave (64 threads) per batch,
// exactly mirroring the reference _lsa (double math, same op order, argmin
// tie-break = lowest column). Fused tail computes the per-batch CE
// correction (matched: full nll minus the EOS nll already counted) and the
// L1 time-loss partial.
// ---------------------------------------------------------------------------
__global__ __launch_bounds__(64) void hungarian_kernel(
    const float* __restrict__ Cg, const float* __restrict__ logits,
    const float* __restrict__ ptime, const int* __restrict__ labels,
    const float* __restrict__ tstamp, const float* __restrict__ logZ,
    float* __restrict__ cpart, float* __restrict__ tpart)
{
    const int b = blockIdx.x;
    const int t = threadIdx.x;

    __shared__ double cost[NN][QQ];     // 12.8 KB
    __shared__ double u[NN + 1];
    __shared__ int p[QQ + 1];
    __shared__ int way[QQ + 1];
    __shared__ int qsl[NN];

    for (int idx = t; idx < NN * QQ; idx += 64)
        cost[idx / QQ][idx % QQ] = (double)Cg[(size_t)b * NN * QQ + idx];
    for (int idx = t; idx <= QQ; idx += 64) p[idx] = 0;
    if (t <= NN) u[t] = 0.0;

    // Each lane owns columns jc0 = t+1 and (if <=100) jc1 = t+65 (1-based).
    const int jc0 = t + 1;
    const int jc1 = t + 65;
    const bool has2 = (jc1 <= QQ);
    double v0 = 0.0, v1 = 0.0;          // potentials for owned columns
    const double INF = __builtin_inf();

    __syncthreads();

    for (int i = 1; i <= NN; ++i) {
        double minv0 = INF, minv1 = INF;
        bool used0 = false, used1 = false;
        if (t == 0) p[0] = i;
        int j0 = 0;
        __syncthreads();                 // p[0] visible

        while (true) {
            if (j0 == jc0) used0 = true;
            if (j0 == jc1) used1 = true;
            int i0 = p[j0];
            double ui0 = u[i0];

            double bestv = INF;
            int bestj = 0x7FFFFFFF;
            if (!used0) {
                double cur = cost[i0 - 1][jc0 - 1] - ui0 - v0;
                if (cur < minv0) { minv0 = cur; way[jc0] = j0; }
                bestv = minv0; bestj = jc0;
            }
            if (has2 && !used1) {
                double cur = cost[i0 - 1][jc1 - 1] - ui0 - v1;
                if (cur < minv1) { minv1 = cur; way[jc1] = j0; }
                if (minv1 < bestv) { bestv = minv1; bestj = jc1; }  // tie keeps jc0
            }
            // wave-wide argmin butterfly: result in ALL lanes (no broadcast)
            #pragma unroll
            for (int s = 1; s < 64; s <<= 1) {
                double ov = __shfl_xor(bestv, s, 64);
                int oj = __shfl_xor(bestj, s, 64);
                if (ov < bestv || (ov == bestv && oj < bestj)) { bestv = ov; bestj = oj; }
            }
            double delta = bestv;
            int j1 = bestj;

            __syncthreads();             // all u reads done before u writes

            if (t == 0) u[p[0]] += delta;                 // column 0 (always used)
            if (used0) { u[p[jc0]] += delta; v0 -= delta; } else { minv0 -= delta; }
            if (has2) {
                if (used1) { u[p[jc1]] += delta; v1 -= delta; } else { minv1 -= delta; }
            }
            j0 = j1;
            __syncthreads();             // u/way writes visible
            if (p[j0] == 0) break;       // uniform
        }

        if (t == 0) {                    // augment along alternating path
            int jj = j0;
            while (jj != 0) {
                int jn = way[jj];
                p[jj] = p[jn];
                jj = jn;
            }
        }
        __syncthreads();
    }

    // extract matches: qsl[target] = column
    for (int idx = t + 1; idx <= QQ; idx += 64) {
        int r = p[idx];
        if (r > 0) qsl[r - 1] = idx - 1;
    }
    __syncthreads();

    // fused tail: CE correction + time-loss partials for this batch
    float corr = 0.f, tl = 0.f;
    if (t < NN) {
        int qcol = qsl[t];
        int lab = labels[b * NN + t];
        int bq = b * QQ + qcol;
        float lz = logZ[bq];
        float lgm = logits[(size_t)bq * CC + lab];
        float lg0 = logits[(size_t)bq * CC];
        corr = (lz - lgm) - EOS_COEF * (lz - lg0);
        tl = fabsf(ptime[bq] - tstamp[b * NN + t]);
    }
    #pragma unroll
    for (int s = 1; s < 64; s <<= 1) {
        corr += __shfl_xor(corr, s, 64);
        tl   += __shfl_xor(tl, s, 64);
    }
    if (t == 0) { cpart[b] = corr; tpart[b] = tl; }
}

// ---------------------------------------------------------------------------
// Kernel 3: final reduce of partials -> scalar loss.
// ---------------------------------------------------------------------------
__global__ __launch_bounds__(256) void fin_kernel(
    const float* __restrict__ lsepart, const float* __restrict__ cpart,
    const float* __restrict__ tpart, float* __restrict__ out)
{
    const int t = threadIdx.x;
    float a0 = 0.f;
    for (int i = t; i < 1600; i += 256) a0 += lsepart[i];
    float a1 = (t < BB) ? cpart[t] : 0.f;
    float a2 = (t < BB) ? tpart[t] : 0.f;
    __shared__ float r0[256], r1[256], r2[256];
    r0[t] = a0; r1[t] = a1; r2[t] = a2;
    __syncthreads();
    for (int s = 128; s > 0; s >>= 1) {
        if (t < s) { r0[t] += r0[t + s]; r1[t] += r1[t + s]; r2[t] += r2[t + s]; }
        __syncthreads();
    }
    if (t == 0) {
        const float sum_w = (float)(BB * NN) * 1.0f
                          + (float)(BB * (QQ - NN)) * EOS_COEF;   // 1561.6, constant
        float loss_ce = (EOS_COEF * r0[0] + r1[0]) / sum_w;
        float loss_t  = r2[0] / (float)(BB * NN);
        out[0] = loss_ce + TIME_WEIGHT * loss_t;
    }
}

// ---------------------------------------------------------------------------
// Workspace layout (bytes):
//   [0,      25600)  : float logZ[6400]
//   [25600, 435200)  : float Cg[64*16*100]
//   [435200, 441600) : float lsepart[1600]
//   [441600, 441856) : float cpart[64]
//   [441856, 442112) : float tpart[64]
// All entries are written before being read each call (no memset needed).
// ---------------------------------------------------------------------------
extern "C" void kernel_launch(void* const* d_in, const int* in_sizes, int n_in,
                              void* d_out, int out_size, void* d_ws, size_t ws_size,
                              hipStream_t stream) {
    const float* logits = (const float*)d_in[0];   // [B,Q,2048]
    const float* ptime  = (const float*)d_in[1];   // [B,Q,1]
    const int*   labels = (const int*)d_in[2];     // [B,N]
    const float* tstamp = (const float*)d_in[3];   // [B,N,1]
    float* out = (float*)d_out;

    char* ws = (char*)d_ws;
    float* logZ    = (float*)ws;
    float* Cg      = (float*)(ws + 25600);
    float* lsepart = (float*)(ws + 435200);
    float* cpart   = (float*)(ws + 441600);
    float* tpart   = (float*)(ws + 441856);

    lse_cost_kernel<<<1600, 256, 0, stream>>>(logits, ptime, labels, tstamp,
                                              logZ, Cg, lsepart);
    hungarian_kernel<<<BB, 64, 0, stream>>>(Cg, logits, ptime, labels, tstamp,
                                            logZ, cpart, tpart);
    fin_kernel<<<1, 256, 0, stream>>>(lsepart, cpart, tpart, out);
}

// Round 3
// 123.335 us; speedup vs baseline: 1.1041x; 1.0130x over previous
//
#include <hip/hip_runtime.h>
#include <hip/hip_bf16.h>
#include <math.h>

// Problem constants
#define BB 64
#define QQ 100
#define NN 16
#define CC 2048            // NUM_CLASSES + 1
#define TIME_WEIGHT 2.0f
#define EOS_COEF 0.1f

// ---------------------------------------------------------------------------
// Kernel 1: per (b,q) row (one wave each):
//   logZ[b,q] = logsumexp(logits[b,q,:])
//   Cg[b][n][q] = -softmax[label_n] + 2*|pt - ts_n|   (transposed cost matrix)
//   lsepart[block] = sum over 4 rows of (logZ - logit[class 0])   [EOS nll]
// Block 0 additionally zero-inits the atomic accumulators for kernel 2.
// 1600 blocks x 256 threads (4 waves = 4 rows per block).
// ---------------------------------------------------------------------------
__global__ __launch_bounds__(256) void lse_cost_kernel(
    const float* __restrict__ logits, const float* __restrict__ ptime,
    const int* __restrict__ labels, const float* __restrict__ tstamp,
    float* __restrict__ logZ, float* __restrict__ Cg,
    float* __restrict__ lsepart, float* __restrict__ sums, int* __restrict__ counter)
{
    if (blockIdx.x == 0 && threadIdx.x == 0) {
        sums[0] = 0.f; sums[1] = 0.f; *counter = 0;
    }
    const int wave = threadIdx.x >> 6;
    const int lane = threadIdx.x & 63;
    const int bq = blockIdx.x * 4 + wave;          // < 6400
    const int b = bq / QQ, q = bq % QQ;
    const float4* row4 = (const float4*)(logits + (size_t)bq * CC);

    float4 v[8];
    #pragma unroll
    for (int c = 0; c < 8; ++c) v[c] = row4[c * 64 + lane];

    float m = -INFINITY;
    #pragma unroll
    for (int c = 0; c < 8; ++c)
        m = fmaxf(m, fmaxf(fmaxf(v[c].x, v[c].y), fmaxf(v[c].z, v[c].w)));
    #pragma unroll
    for (int s = 1; s < 64; s <<= 1) m = fmaxf(m, __shfl_xor(m, s, 64));

    float sum = 0.f;
    #pragma unroll
    for (int c = 0; c < 8; ++c)
        sum += expf(v[c].x - m) + expf(v[c].y - m) +
               expf(v[c].z - m) + expf(v[c].w - m);
    #pragma unroll
    for (int s = 1; s < 64; s <<= 1) sum += __shfl_xor(sum, s, 64);

    const float lz = m + logf(sum);
    if (lane == 0) logZ[bq] = lz;

    // cost-matrix entries (lanes 0..15: one target each)
    const float pt = ptime[bq];
    if (lane < NN) {
        int lab = labels[b * NN + lane];
        float lg = logits[(size_t)bq * CC + lab];     // L1-hot gather (same row)
        float cc = -expf(lg - lz);
        float ct = fabsf(pt - tstamp[b * NN + lane]);
        float val = cc + TIME_WEIGHT * ct;
        if (isnan(val)) val = 100.0f;
        else if (isinf(val)) val = (val > 0.f) ? 100.0f : -100.0f;
        Cg[((size_t)b * NN + lane) * QQ + q] = val;
    }

    // EOS nll partial: nll0 = logZ - logit[class 0]
    __shared__ float red[4];
    if (lane == 0) red[wave] = lz - logits[(size_t)bq * CC];
    __syncthreads();
    if (threadIdx.x == 0)
        lsepart[blockIdx.x] = red[0] + red[1] + red[2] + red[3];
}

// ---------------------------------------------------------------------------
// Kernel 2: Jonker-Volgenant assignment, one wave per batch, register-
// resident state (p/way/v distributed per owning lane, u distributed in
// lanes 0..15), barrier-free inner loop. Operation-for-operation identical
// FP arithmetic to the reference _lsa:
//  - u[i0] / v[free] are provably unmodified during a Dijkstra (p injective),
//    so reads use pre-Dijkstra register values — exact.
//  - u[p[used]] += delta  ==  per-lane "if(inTree) ureg += delta" with the
//    identical per-iteration addition sequence — exact.
// Fused tail: CE correction + L1 time partials -> device atomics; the last
// block of the 64 folds lsepart and writes the final scalar loss.
// ---------------------------------------------------------------------------
__global__ __launch_bounds__(64) void hungarian_kernel(
    const float* __restrict__ Cg, const float* __restrict__ logits,
    const float* __restrict__ ptime, const int* __restrict__ labels,
    const float* __restrict__ tstamp, const float* __restrict__ logZ,
    const float* __restrict__ lsepart, float* __restrict__ sums,
    int* __restrict__ counter, float* __restrict__ out)
{
    const int b = blockIdx.x;
    const int t = threadIdx.x;

    __shared__ double cost[NN * QQ];    // 12.8 KB
    __shared__ int qsl[NN];

    for (int idx = t; idx < NN * QQ; idx += 64)
        cost[idx] = (double)Cg[(size_t)b * NN * QQ + idx];
    __syncthreads();

    // Lane t owns columns jc0 = t+1 and (if <=100) jc1 = t+65 (1-based).
    const int jc0 = t + 1;
    const int jc1 = t + 65;
    const bool has2 = (jc1 <= QQ);
    double v0 = 0.0, v1 = 0.0;          // column potentials (owned)
    double ureg = 0.0;                  // lane r holds u[r+1] (lanes 0..15)
    int preg0 = 0, preg1 = 0;           // p[jc0], p[jc1] (0 = free column)
    const double INF = __builtin_inf();

    for (int i = 1; i <= NN; ++i) {
        double minv0 = INF, minv1 = INF;
        bool used0 = false, used1 = false;
        int way0 = 0, way1 = 0;
        bool inTree = (t == i - 1);     // p[0] = i enters the tree at start
        int j0 = 0;
        int i0 = i;                      // p[0]

        while (true) {
            used0 |= (j0 == jc0);
            used1 |= (j0 == jc1);
            inTree = inTree || (t == i0 - 1);
            const double u_i0 = __shfl(ureg, i0 - 1, 64);
            const double* crow = &cost[(i0 - 1) * QQ];

            double bestv = INF;
            int bestj = 0x7FFFFFFF;
            if (!used0) {
                double cur = crow[jc0 - 1] - u_i0 - v0;
                if (cur < minv0) { minv0 = cur; way0 = j0; }
                bestv = minv0; bestj = jc0;
            }
            if (has2 && !used1) {
                double cur = crow[jc1 - 1] - u_i0 - v1;
                if (cur < minv1) { minv1 = cur; way1 = j0; }
                if (minv1 < bestv) { bestv = minv1; bestj = jc1; }  // tie keeps jc0
            }
            // wave-wide argmin butterfly, tie-break lowest column
            #pragma unroll
            for (int s = 1; s < 64; s <<= 1) {
                double ov = __shfl_xor(bestv, s, 64);
                int oj = __shfl_xor(bestj, s, 64);
                if (ov < bestv || (ov == bestv && oj < bestj)) { bestv = ov; bestj = oj; }
            }
            const double delta = bestv;
            const int j1 = bestj;

            if (inTree) ureg += delta;                   // u[p[used]] += delta
            if (used0) v0 -= delta; else minv0 -= delta; // v[used]-=d / minv[free]-=d
            if (has2) { if (used1) v1 -= delta; else minv1 -= delta; }

            j0 = j1;
            // p[j0] via one shuffle (j0 uniform)
            int psrc = (j0 <= 64) ? preg0 : preg1;
            int plane = (j0 <= 64) ? (j0 - 1) : (j0 - 65);
            int pj = __shfl(psrc, plane, 64);
            if (pj == 0) break;
            i0 = pj;
        }

        // augment along the alternating path (uniform walk, all lanes)
        while (j0 != 0) {
            int wsrc = (j0 <= 64) ? way0 : way1;
            int wlane = (j0 <= 64) ? (j0 - 1) : (j0 - 65);
            int jn = __shfl(wsrc, wlane, 64);
            int pv;
            if (jn == 0) pv = i;
            else {
                int psrc = (jn <= 64) ? preg0 : preg1;
                int plane = (jn <= 64) ? (jn - 1) : (jn - 65);
                pv = __shfl(psrc, plane, 64);
            }
            if (j0 == jc0) preg0 = pv;
            if (has2 && j0 == jc1) preg1 = pv;
            j0 = jn;
        }
    }

    // extract matches: qsl[target row] = column
    if (preg0 > 0) qsl[preg0 - 1] = jc0 - 1;
    if (has2 && preg1 > 0) qsl[preg1 - 1] = jc1 - 1;
    __syncthreads();

    // fused tail: CE correction + time-loss partials for this batch
    float corr = 0.f, tl = 0.f;
    if (t < NN) {
        int qcol = qsl[t];
        int lab = labels[b * NN + t];
        int bq = b * QQ + qcol;
        float lz = logZ[bq];
        float lgm = logits[(size_t)bq * CC + lab];
        float lg0 = logits[(size_t)bq * CC];
        corr = (lz - lgm) - EOS_COEF * (lz - lg0);
        tl = fabsf(ptime[bq] - tstamp[b * NN + t]);
    }
    #pragma unroll
    for (int s = 1; s < 64; s <<= 1) {
        corr += __shfl_xor(corr, s, 64);
        tl   += __shfl_xor(tl, s, 64);
    }

    int old = 0;
    if (t == 0) {
        atomicAdd(&sums[0], corr);
        atomicAdd(&sums[1], tl);
        __threadfence();                 // release partials before counter bump
        old = atomicAdd(counter, 1);
    }
    old = __shfl(old, 0, 64);
    if (old == BB - 1) {                 // last block finalizes
        __threadfence();                 // acquire others' partials
        float r0 = 0.f;
        #pragma unroll
        for (int k = 0; k < 25; ++k) r0 += lsepart[t + 64 * k];   // 1600 = 64*25
        #pragma unroll
        for (int s = 1; s < 64; s <<= 1) r0 += __shfl_xor(r0, s, 64);
        if (t == 0) {
            float s0 = atomicAdd(&sums[0], 0.0f);
            float s1 = atomicAdd(&sums[1], 0.0f);
            const float sum_w = (float)(BB * NN) * 1.0f
                              + (float)(BB * (QQ - NN)) * EOS_COEF;   // 1561.6
            float loss_ce = (EOS_COEF * r0 + s0) / sum_w;
            float loss_t  = s1 / (float)(BB * NN);
            out[0] = loss_ce + TIME_WEIGHT * loss_t;
        }
    }
}

// ---------------------------------------------------------------------------
// Workspace layout (bytes):
//   [0,      25600)  : float logZ[6400]
//   [25600, 435200)  : float Cg[64*16*100]
//   [435200, 441600) : float lsepart[1600]
//   [441600, 441608) : float sums[2]   {ce_corr, time}   (zeroed by kernel 1)
//   [441608, 441612) : int   counter                     (zeroed by kernel 1)
// ---------------------------------------------------------------------------
extern "C" void kernel_launch(void* const* d_in, const int* in_sizes, int n_in,
                              void* d_out, int out_size, void* d_ws, size_t ws_size,
                              hipStream_t stream) {
    const float* logits = (const float*)d_in[0];   // [B,Q,2048]
    const float* ptime  = (const float*)d_in[1];   // [B,Q,1]
    const int*   labels = (const int*)d_in[2];     // [B,N]
    const float* tstamp = (const float*)d_in[3];   // [B,N,1]
    float* out = (float*)d_out;

    char* ws = (char*)d_ws;
    float* logZ    = (float*)ws;
    float* Cg      = (float*)(ws + 25600);
    float* lsepart = (float*)(ws + 435200);
    float* sums    = (float*)(ws + 441600);
    int*   counter = (int*)(ws + 441608);

    lse_cost_kernel<<<1600, 256, 0, stream>>>(logits, ptime, labels, tstamp,
                                              logZ, Cg, lsepart, sums, counter);
    hungarian_kernel<<<BB, 64, 0, stream>>>(Cg, logits, ptime, labels, tstamp,
                                            logZ, lsepart, sums, counter, out);
}